// Round 1
// baseline (207.377 us; speedup 1.0000x reference)
//
#include <hip/hip_runtime.h>

#define NC 64
#define NF 64
#define HID 128

__device__ __forceinline__ float wshfl(float v, int src)   { return __shfl(v, src, 64); }
__device__ __forceinline__ float wshfl_up(float v, int d)  { return __shfl_up(v, d, 64); }
__device__ __forceinline__ float wshfl_dn(float v, int d)  { return __shfl_down(v, d, 64); }
__device__ __forceinline__ float wshfl_xor(float v, int m) { return __shfl_xor(v, m, 64); }

__device__ __forceinline__ float wave_sum(float v) {
#pragma unroll
    for (int m = 32; m >= 1; m >>= 1) v += wshfl_xor(v, m);
    return v;
}

// inclusive prefix-sum across the wave
__device__ __forceinline__ float wave_iscan_add(float v, int lane) {
#pragma unroll
    for (int d = 1; d < 64; d <<= 1) {
        float t = wshfl_up(v, d);
        if (lane >= d) v += t;
    }
    return v;
}

// inclusive prefix-product across the wave
__device__ __forceinline__ float wave_iscan_mul(float v, int lane) {
#pragma unroll
    for (int d = 1; d < 64; d <<= 1) {
        float t = wshfl_up(v, d);
        if (lane >= d) v *= t;
    }
    return v;
}

// MLP: h = relu(p @ W1 + b1); out = h @ W2 + b2.  P points per lane.
template <int P>
__device__ __forceinline__ void run_mlp(const float* __restrict__ W1,
                                        const float* __restrict__ b1,
                                        const float* __restrict__ W2,
                                        const float* __restrict__ b2,
                                        const float px[P], const float py[P], const float pz[P],
                                        float acc[P][4]) {
#pragma unroll
    for (int p = 0; p < P; ++p) {
#pragma unroll
        for (int k = 0; k < 4; ++k) acc[p][k] = b2[k];
    }
#pragma unroll
    for (int j = 0; j < HID; ++j) {
        const float w10 = W1[j], w11 = W1[HID + j], w12 = W1[2 * HID + j];
        const float bb  = b1[j];
        const float w20 = W2[4 * j + 0], w21 = W2[4 * j + 1];
        const float w22 = W2[4 * j + 2], w23 = W2[4 * j + 3];
#pragma unroll
        for (int p = 0; p < P; ++p) {
            float h = fmaf(px[p], w10, fmaf(py[p], w11, fmaf(pz[p], w12, bb)));
            h = fmaxf(h, 0.0f);
            acc[p][0] = fmaf(h, w20, acc[p][0]);
            acc[p][1] = fmaf(h, w21, acc[p][1]);
            acc[p][2] = fmaf(h, w22, acc[p][2]);
            acc[p][3] = fmaf(h, w23, acc[p][3]);
        }
    }
}

extern "C" __global__ void __launch_bounds__(256)
nerf_fused(const float* __restrict__ rays,
           const float* __restrict__ u_coarse,
           const float* __restrict__ u_fine,
           const float* __restrict__ u_jitter,
           const float* __restrict__ W1,
           const float* __restrict__ b1,
           const float* __restrict__ W2,
           const float* __restrict__ b2,
           float* __restrict__ out) {
    const int lane = threadIdx.x & 63;
    const int wv   = threadIdx.x >> 6;   // 0..3, one wave per ray
    const int ray  = (blockIdx.x << 2) + wv;

    __shared__ float s_cdf[4][65];
    __shared__ float s_zc [4][64];
    __shared__ float s_zf [4][64];
    __shared__ float s_za [4][130];

    // ---- ray data (wave-uniform) ----
    const float* rp = rays + ray * 8;
    const float ox = rp[0], oy = rp[1], oz = rp[2];
    const float dx = rp[3], dy = rp[4], dz = rp[5];
    const float nearv = rp[6], farv = rp[7];

    // ================= coarse pass =================
    const float uc = u_coarse[(ray << 6) + lane];
    const float zs = ((float)lane + uc) * 0.015625f;          // (i + u)/64
    const float zc = nearv * (1.0f - zs) + farv * zs;

    {
        float px[1] = { fmaf(zc, dx, ox) };
        float py[1] = { fmaf(zc, dy, oy) };
        float pz[1] = { fmaf(zc, dz, oz) };
        float o1[1][4];
        run_mlp<1>(W1, b1, W2, b2, px, py, pz, o1);

        float znext = wshfl_dn(zc, 1);
        float delta = (lane == 63) ? (farv - zc) : (znext - zc);
        float alpha = 1.0f - __expf(-delta * fmaxf(o1[0][3], 0.0f));

        float f  = 1.0f - alpha + 1e-10f;
        float ip = wave_iscan_mul(f, lane);
        float Te = wshfl_up(ip, 1);
        if (lane == 0) Te = 1.0f;
        float w = alpha * Te;

        float rc = wave_sum(w * o1[0][0]);
        float gc = wave_sum(w * o1[0][1]);
        float bc = wave_sum(w * o1[0][2]);
        float dc = wave_sum(w * zc);

        // ---- pdf / cdf for fine sampling ----
        float wp = w + 1e-5f;
        float cs = wave_iscan_add(wp, lane);
        float total = wshfl(cs, 63);
        if (lane == 0) s_cdf[wv][0] = 0.0f;
        s_cdf[wv][lane + 1] = cs / total;
        s_zc[wv][lane] = zc;

        // stash coarse results for the final write (keep in regs via lane0)
        if (lane == 0) {
            float4* op = (float4*)(out + ray * 8);
            op[0] = make_float4(rc, gc, bc, dc);
        }
    }

    // ================= fine sampling =================
    const float uf = u_fine[(ray << 6) + lane];
    const float uj = u_jitter[(ray << 6) + lane];

    int lo = 0, hi = 65;            // upper_bound over cdf[0..64]
#pragma unroll
    for (int it = 0; it < 7; ++it) {
        if (lo < hi) {
            int mid = (lo + hi) >> 1;
            if (s_cdf[wv][mid] <= uf) lo = mid + 1; else hi = mid;
        }
    }
    float ind = fmaxf((float)lo - 1.0f, 0.0f);
    float zfs = (ind + uj) * 0.015625f;
    float zfv = nearv * (1.0f - zfs) + farv * zfs;

    // ---- bitonic sort of fine z across the wave (ascending) ----
    float v = zfv;
#pragma unroll
    for (int k = 2; k <= 64; k <<= 1) {
#pragma unroll
        for (int j = k >> 1; j > 0; j >>= 1) {
            float other = wshfl_xor(v, j);
            bool asc = ((lane & k) == 0);
            bool low = ((lane & j) == 0);
            float mn = fminf(v, other), mx = fmaxf(v, other);
            v = (asc == low) ? mn : mx;
        }
    }
    s_zf[wv][lane] = v;

    // ---- merge ranks: z_all = stable-sort(concat(zc, zf)) ----
    // coarse element: rank = lane + #{zf_sorted < zc}   (lower_bound)
    int lof = 0, hif = 64;
#pragma unroll
    for (int it = 0; it < 7; ++it) {
        if (lof < hif) {
            int mid = (lof + hif) >> 1;
            if (s_zf[wv][mid] < zc) lof = mid + 1; else hif = mid;
        }
    }
    // fine element: rank = lane + #{zc <= v}            (upper_bound)
    int loc = 0, hic = 64;
#pragma unroll
    for (int it = 0; it < 7; ++it) {
        if (loc < hic) {
            int mid = (loc + hic) >> 1;
            if (s_zc[wv][mid] <= v) loc = mid + 1; else hic = mid;
        }
    }
    s_za[wv][lane + lof] = zc;
    s_za[wv][lane + loc] = v;

    // ================= fine pass (128 samples, 2 per lane) =================
    const float z0 = s_za[wv][2 * lane];
    const float z1 = s_za[wv][2 * lane + 1];
    const float z2 = (lane == 63) ? farv : s_za[wv][2 * lane + 2];

    float fx[2] = { fmaf(z0, dx, ox), fmaf(z1, dx, ox) };
    float fy[2] = { fmaf(z0, dy, oy), fmaf(z1, dy, oy) };
    float fz[2] = { fmaf(z0, dz, oz), fmaf(z1, dz, oz) };
    float o2[2][4];
    run_mlp<2>(W1, b1, W2, b2, fx, fy, fz, o2);

    float d0 = z1 - z0;
    float d1 = z2 - z1;
    float a0 = 1.0f - __expf(-d0 * fmaxf(o2[0][3], 0.0f));
    float a1 = 1.0f - __expf(-d1 * fmaxf(o2[1][3], 0.0f));
    float f0 = 1.0f - a0 + 1e-10f;
    float f1 = 1.0f - a1 + 1e-10f;

    float pl = f0 * f1;
    float ip = wave_iscan_mul(pl, lane);
    float Ee = wshfl_up(ip, 1);
    if (lane == 0) Ee = 1.0f;

    float w0 = a0 * Ee;
    float w1 = a1 * Ee * f0;

    float rf = wave_sum(fmaf(w0, o2[0][0], w1 * o2[1][0]));
    float gf = wave_sum(fmaf(w0, o2[0][1], w1 * o2[1][1]));
    float bf = wave_sum(fmaf(w0, o2[0][2], w1 * o2[1][2]));
    float df = wave_sum(fmaf(w0, z0, w1 * z1));

    if (lane == 0) {
        float4* op = (float4*)(out + ray * 8);
        op[1] = make_float4(rf, gf, bf, df);
    }
}

extern "C" void kernel_launch(void* const* d_in, const int* in_sizes, int n_in,
                              void* d_out, int out_size, void* d_ws, size_t ws_size,
                              hipStream_t stream) {
    const float* rays = (const float*)d_in[0];
    const float* uc   = (const float*)d_in[1];
    const float* uf   = (const float*)d_in[2];
    const float* uj   = (const float*)d_in[3];
    const float* W1   = (const float*)d_in[4];
    const float* b1   = (const float*)d_in[5];
    const float* W2   = (const float*)d_in[6];
    const float* b2   = (const float*)d_in[7];
    float* o          = (float*)d_out;

    const int R = in_sizes[0] / 8;
    dim3 grid(R / 4), block(256);
    hipLaunchKernelGGL(nerf_fused, grid, block, 0, stream,
                       rays, uc, uf, uj, W1, b1, W2, b2, o);
}

// Round 3
// 128.782 us; speedup vs baseline: 1.6103x; 1.6103x over previous
//
#include <hip/hip_runtime.h>

#define HID 128

typedef _Float16 f16x8 __attribute__((ext_vector_type(8)));
typedef _Float16 f16x2 __attribute__((ext_vector_type(2)));
typedef float f32x4 __attribute__((ext_vector_type(4)));

union HV { f16x8 v; f16x2 h[4]; };

__device__ __forceinline__ float wshfl(float v, int src)   { return __shfl(v, src, 64); }
__device__ __forceinline__ float wshfl_up(float v, int d)  { return __shfl_up(v, d, 64); }
__device__ __forceinline__ float wshfl_dn(float v, int d)  { return __shfl_down(v, d, 64); }
__device__ __forceinline__ float wshfl_xor(float v, int m) { return __shfl_xor(v, m, 64); }

__device__ __forceinline__ float wave_sum(float v) {
#pragma unroll
    for (int m = 32; m >= 1; m >>= 1) v += wshfl_xor(v, m);
    return v;
}

__device__ __forceinline__ float wave_iscan_add(float v, int lane) {
#pragma unroll
    for (int d = 1; d < 64; d <<= 1) {
        float t = wshfl_up(v, d);
        if (lane >= d) v += t;
    }
    return v;
}

__device__ __forceinline__ float wave_iscan_mul(float v, int lane) {
#pragma unroll
    for (int d = 1; d < 64; d <<= 1) {
        float t = wshfl_up(v, d);
        if (lane >= d) v *= t;
    }
    return v;
}

// One 16-sample MLP tile.  Lane layout:
//   s16 = lane&15  -> sample column (B-frag col, C col)
//   g   = lane>>4  -> k-group: this lane computes h for hidden = 32c + 8g + e
// Layer1 in packed f16 (v_pk_fma_f16), layer2 as 4x mfma_f32_16x16x32_f16 with
// A = W2^T fragments (constant per wave), C initialized with b2 (rows 0-3).
__device__ __forceinline__ f32x4 mlp_tile(float x, float y, float z,
                                          const _Float16* __restrict__ wls,
                                          const f16x8* __restrict__ w2t,
                                          f32x4 cini, int g) {
    const _Float16 xs = (_Float16)x, ys = (_Float16)y, zs = (_Float16)z;
    const f16x2 xp = { xs, xs };
    const f16x2 yp = { ys, ys };
    const f16x2 zp = { zs, zs };
    const f16x2 zero2 = { (_Float16)0, (_Float16)0 };
    f32x4 C = cini;
#pragma unroll
    for (int c = 0; c < 4; ++c) {
        const int hid0 = 32 * c + 8 * g;
        HV w0 = *(const HV*)&wls[hid0];            // W1 row 0
        HV w1 = *(const HV*)&wls[HID + hid0];      // W1 row 1
        HV w2 = *(const HV*)&wls[2 * HID + hid0];  // W1 row 2
        HV bb = *(const HV*)&wls[3 * HID + hid0];  // b1
        HV hb;
#pragma unroll
        for (int r = 0; r < 4; ++r) {
            f16x2 acc = w0.h[r] * xp + bb.h[r];
            acc = w1.h[r] * yp + acc;
            acc = w2.h[r] * zp + acc;
            hb.h[r] = __builtin_elementwise_max(acc, zero2);
        }
        C = __builtin_amdgcn_mfma_f32_16x16x32_f16(w2t[c], hb.v, C, 0, 0, 0);
    }
    return C;
}

extern "C" __global__ void __launch_bounds__(256)
nerf_fused(const float* __restrict__ rays,
           const float* __restrict__ u_coarse,
           const float* __restrict__ u_fine,
           const float* __restrict__ u_jitter,
           const float* __restrict__ W1,
           const float* __restrict__ b1,
           const float* __restrict__ W2,
           const float* __restrict__ b2,
           float* __restrict__ out) {
    const int lane = threadIdx.x & 63;
    const int wv   = threadIdx.x >> 6;   // 0..3, one wave per ray
    const int ray  = (blockIdx.x << 2) + wv;
    const int s16  = lane & 15;
    const int g    = lane >> 4;

    __shared__ _Float16 wls[4 * HID];   // [0:128) W1r0, [128:256) W1r1, [256:384) W1r2, [384:512) b1
    __shared__ float s_cdf [4][65];
    __shared__ float s_zc  [4][64];
    __shared__ float s_zf  [4][64];
    __shared__ float s_za  [4][130];
    __shared__ float s_rgba[4][128][4];

    // ---- stage W1/b1 as f16 into LDS (one copy per block) ----
    {
        const int tid = threadIdx.x;
        if (tid < 192) {
            f16x2 p = { (_Float16)W1[2 * tid], (_Float16)W1[2 * tid + 1] };
            *(f16x2*)&wls[2 * tid] = p;
        } else {
            const int i = tid - 192;   // 0..63 -> b1 pairs
            f16x2 p = { (_Float16)b1[2 * i], (_Float16)b1[2 * i + 1] };
            *(f16x2*)&wls[384 + 2 * i] = p;
        }
    }
    __syncthreads();

    // ---- per-wave constant W2^T fragments (A operand), f16 ----
    f16x8 w2t[4];
#pragma unroll
    for (int c = 0; c < 4; ++c) {
        HV u;
#pragma unroll
        for (int r = 0; r < 4; ++r) {
            const int k0 = 32 * c + 8 * g + 2 * r;
            float a0 = 0.0f, a1 = 0.0f;
            if (s16 < 4) {
                a0 = W2[k0 * 4 + s16];
                a1 = W2[(k0 + 1) * 4 + s16];
            }
            f16x2 p = { (_Float16)a0, (_Float16)a1 };
            u.h[r] = p;
        }
        w2t[c] = u.v;
    }
    // C init: row = g*4+r holds b2[row] for rows 0..3, else 0
    f32x4 cini;
    {
        const float c0 = b2[0], c1 = b2[1], c2 = b2[2], c3 = b2[3];
        cini[0] = (g == 0) ? c0 : 0.0f;
        cini[1] = (g == 0) ? c1 : 0.0f;
        cini[2] = (g == 0) ? c2 : 0.0f;
        cini[3] = (g == 0) ? c3 : 0.0f;
    }

    // ---- ray data (wave-uniform) ----
    const float* rp = rays + ray * 8;
    const float ox = rp[0], oy = rp[1], oz = rp[2];
    const float dx = rp[3], dy = rp[4], dz = rp[5];
    const float nearv = rp[6], farv = rp[7];

    // ================= coarse sampling =================
    const float uc = u_coarse[(ray << 6) + lane];
    const float zsv = ((float)lane + uc) * 0.015625f;
    const float zc = nearv * (1.0f - zsv) + farv * zsv;
    s_zc[wv][lane] = zc;

    // ---- coarse MLP: 4 tiles of 16 samples ----
#pragma unroll
    for (int t = 0; t < 4; ++t) {
        const float zt = s_zc[wv][t * 16 + s16];
        f32x4 C = mlp_tile(fmaf(zt, dx, ox), fmaf(zt, dy, oy), fmaf(zt, dz, oz),
                           wls, w2t, cini, g);
        if (lane < 16) {
            *(float4*)&s_rgba[wv][t * 16 + s16][0] = make_float4(C[0], C[1], C[2], C[3]);
        }
    }

    // ---- coarse composite ----
    {
        const float4 cv = *(const float4*)&s_rgba[wv][lane][0];
        const float znext = wshfl_dn(zc, 1);
        const float delta = (lane == 63) ? (farv - zc) : (znext - zc);
        const float alpha = 1.0f - __expf(-delta * fmaxf(cv.w, 0.0f));

        float f  = 1.0f - alpha + 1e-10f;
        float ip = wave_iscan_mul(f, lane);
        float Te = wshfl_up(ip, 1);
        if (lane == 0) Te = 1.0f;
        const float w = alpha * Te;

        const float rc = wave_sum(w * cv.x);
        const float gc = wave_sum(w * cv.y);
        const float bc = wave_sum(w * cv.z);
        const float dc = wave_sum(w * zc);

        float wp = w + 1e-5f;
        float cs = wave_iscan_add(wp, lane);
        float total = wshfl(cs, 63);
        if (lane == 0) s_cdf[wv][0] = 0.0f;
        s_cdf[wv][lane + 1] = cs / total;

        if (lane == 0) {
            float4* op = (float4*)(out + ray * 8);
            op[0] = make_float4(rc, gc, bc, dc);
        }
    }

    // ================= fine sampling =================
    const float uf = u_fine[(ray << 6) + lane];
    const float uj = u_jitter[(ray << 6) + lane];

    int lo = 0, hi = 65;            // upper_bound over cdf[0..64]
#pragma unroll
    for (int it = 0; it < 7; ++it) {
        if (lo < hi) {
            int mid = (lo + hi) >> 1;
            if (s_cdf[wv][mid] <= uf) lo = mid + 1; else hi = mid;
        }
    }
    const float ind = fmaxf((float)lo - 1.0f, 0.0f);
    const float zfs = (ind + uj) * 0.015625f;
    const float zfv = nearv * (1.0f - zfs) + farv * zfs;

    // ---- bitonic sort of fine z across the wave (ascending) ----
    float v = zfv;
#pragma unroll
    for (int k = 2; k <= 64; k <<= 1) {
#pragma unroll
        for (int j = k >> 1; j > 0; j >>= 1) {
            float other = wshfl_xor(v, j);
            bool asc = ((lane & k) == 0);
            bool low = ((lane & j) == 0);
            float mn = fminf(v, other), mx = fmaxf(v, other);
            v = (asc == low) ? mn : mx;
        }
    }
    s_zf[wv][lane] = v;

    // ---- merge ranks: z_all = stable-sort(concat(zc, zf)) ----
    int lof = 0, hif = 64;          // lower_bound of zc in zf_sorted
#pragma unroll
    for (int it = 0; it < 7; ++it) {
        if (lof < hif) {
            int mid = (lof + hif) >> 1;
            if (s_zf[wv][mid] < zc) lof = mid + 1; else hif = mid;
        }
    }
    int loc = 0, hic = 64;          // upper_bound of v in zc
#pragma unroll
    for (int it = 0; it < 7; ++it) {
        if (loc < hic) {
            int mid = (loc + hic) >> 1;
            if (s_zc[wv][mid] <= v) loc = mid + 1; else hic = mid;
        }
    }
    s_za[wv][lane + lof] = zc;
    s_za[wv][lane + loc] = v;

    // ---- fine MLP: 8 tiles of 16 samples ----
#pragma unroll
    for (int t = 0; t < 8; ++t) {
        const float zt = s_za[wv][t * 16 + s16];
        f32x4 C = mlp_tile(fmaf(zt, dx, ox), fmaf(zt, dy, oy), fmaf(zt, dz, oz),
                           wls, w2t, cini, g);
        if (lane < 16) {
            *(float4*)&s_rgba[wv][t * 16 + s16][0] = make_float4(C[0], C[1], C[2], C[3]);
        }
    }

    // ---- fine composite (2 samples per lane) ----
    {
        const float z0 = s_za[wv][2 * lane];
        const float z1 = s_za[wv][2 * lane + 1];
        const float z2 = (lane == 63) ? farv : s_za[wv][2 * lane + 2];
        const float4 v0 = *(const float4*)&s_rgba[wv][2 * lane][0];
        const float4 v1 = *(const float4*)&s_rgba[wv][2 * lane + 1][0];

        const float d0 = z1 - z0;
        const float d1 = z2 - z1;
        const float a0 = 1.0f - __expf(-d0 * fmaxf(v0.w, 0.0f));
        const float a1 = 1.0f - __expf(-d1 * fmaxf(v1.w, 0.0f));
        const float f0 = 1.0f - a0 + 1e-10f;
        const float f1 = 1.0f - a1 + 1e-10f;

        float pl = f0 * f1;
        float ip = wave_iscan_mul(pl, lane);
        float Ee = wshfl_up(ip, 1);
        if (lane == 0) Ee = 1.0f;

        const float w0 = a0 * Ee;
        const float w1 = a1 * Ee * f0;

        const float rf = wave_sum(fmaf(w0, v0.x, w1 * v1.x));
        const float gf = wave_sum(fmaf(w0, v0.y, w1 * v1.y));
        const float bf = wave_sum(fmaf(w0, v0.z, w1 * v1.z));
        const float df = wave_sum(fmaf(w0, z0, w1 * z1));

        if (lane == 0) {
            float4* op = (float4*)(out + ray * 8);
            op[1] = make_float4(rf, gf, bf, df);
        }
    }
}

extern "C" void kernel_launch(void* const* d_in, const int* in_sizes, int n_in,
                              void* d_out, int out_size, void* d_ws, size_t ws_size,
                              hipStream_t stream) {
    const float* rays = (const float*)d_in[0];
    const float* uc   = (const float*)d_in[1];
    const float* uf   = (const float*)d_in[2];
    const float* uj   = (const float*)d_in[3];
    const float* W1   = (const float*)d_in[4];
    const float* b1   = (const float*)d_in[5];
    const float* W2   = (const float*)d_in[6];
    const float* b2   = (const float*)d_in[7];
    float* o          = (float*)d_out;

    const int R = in_sizes[0] / 8;
    dim3 grid(R / 4), block(256);
    hipLaunchKernelGGL(nerf_fused, grid, block, 0, stream,
                       rays, uc, uf, uj, W1, b1, W2, b2, o);
}